// Round 1
// baseline (33812.445 us; speedup 1.0000x reference)
//
#include <hip/hip_runtime.h>
#include <math.h>

#define B_DIM 4
#define T_DIM 4096
#define C_DIM 1024
#define BT    (B_DIM*T_DIM)            // 16384
#define BTC   ((size_t)BT*(size_t)C_DIM) // 16777216

// ---------------------------------------------------------------------------
// Generic fp32 tiled matmul.
//   TB=1: C[m,n] = sum_k A[m,k]*B[n,k]      (B stored [N,K] row-major)
//   TB=0: C[m,n] = sum_k A[m,k]*B[k,n]      (B stored [K,N] row-major)
//   HAS_A2: A_eff[m,k] = A[m,k]*A2[m,k]
//   out = alpha*acc + (HAS_D ? beta*D[m,n] : 0)
// Requires M%BM==0, N%BN==0, K%BK==0, K%4==0. 256 threads.
// ---------------------------------------------------------------------------
template<int BM, int BN, int BK, int TM, int TN, bool TB, bool HAS_A2, bool HAS_D>
__launch_bounds__(256)
__global__ void mm_kernel(const float* __restrict__ A,
                          const float* __restrict__ Bmat,
                          const float* __restrict__ A2,
                          const float* __restrict__ Dmat,
                          float* __restrict__ C,
                          int M, int N, int K, float alpha, float beta)
{
    constexpr int NG = TN / 4;   // 4-wide column groups per thread
    __shared__ float As[BK][BM + 4];
    __shared__ float Bs[BK][BN + 4];

    const int tid = threadIdx.x;
    const int m0 = blockIdx.y * BM;
    const int n0 = blockIdx.x * BN;
    const int tx = tid & 15;
    const int ty = tid >> 4;

    float acc[TM][TN];
#pragma unroll
    for (int i = 0; i < TM; ++i)
#pragma unroll
        for (int j = 0; j < TN; ++j) acc[i][j] = 0.f;

    for (int k0 = 0; k0 < K; k0 += BK) {
        // ---- A tile (BM x BK), stored transposed As[k][m]
        {
            const int r0 = tid >> 2;
            const int kq = (tid & 3) * 4;
#pragma unroll
            for (int r = 0; r < BM; r += 64) {
                const int row = r + r0;
                float4 a = *(const float4*)(A + (size_t)(m0 + row) * K + k0 + kq);
                if (HAS_A2) {
                    float4 a2 = *(const float4*)(A2 + (size_t)(m0 + row) * K + k0 + kq);
                    a.x *= a2.x; a.y *= a2.y; a.z *= a2.z; a.w *= a2.w;
                }
                As[kq + 0][row] = a.x; As[kq + 1][row] = a.y;
                As[kq + 2][row] = a.z; As[kq + 3][row] = a.w;
            }
        }
        // ---- B tile
        if (TB) {
            const int r0 = tid >> 2;
            const int kq = (tid & 3) * 4;
#pragma unroll
            for (int r = 0; r < BN; r += 64) {
                const int row = r + r0;
                float4 b = *(const float4*)(Bmat + (size_t)(n0 + row) * K + k0 + kq);
                Bs[kq + 0][row] = b.x; Bs[kq + 1][row] = b.y;
                Bs[kq + 2][row] = b.z; Bs[kq + 3][row] = b.w;
            }
        } else {
            constexpr int CPR = BN / 4;      // float4s per row
            constexpr int RPP = 256 / CPR;   // rows per pass
            const int rr = tid / CPR;
            const int cc = (tid % CPR) * 4;
#pragma unroll
            for (int r = 0; r < BK; r += RPP) {
                float4 b = *(const float4*)(Bmat + (size_t)(k0 + r + rr) * N + n0 + cc);
                *(float4*)(&Bs[r + rr][cc]) = b;
            }
        }
        __syncthreads();

#pragma unroll
        for (int kk = 0; kk < BK; ++kk) {
            float a[TM], b[TN];
#pragma unroll
            for (int i = 0; i < TM; i += 4)
                *(float4*)(&a[i]) = *(const float4*)(&As[kk][ty * TM + i]);
#pragma unroll
            for (int g = 0; g < NG; ++g)
                *(float4*)(&b[g * 4]) = *(const float4*)(&Bs[kk][g * (BN / 2) + tx * 4]);
#pragma unroll
            for (int i = 0; i < TM; ++i)
#pragma unroll
                for (int j = 0; j < TN; ++j)
                    acc[i][j] = fmaf(a[i], b[j], acc[i][j]);
        }
        __syncthreads();
    }

#pragma unroll
    for (int i = 0; i < TM; ++i) {
        const size_t rbase = (size_t)(m0 + ty * TM + i) * N + n0;
#pragma unroll
        for (int g = 0; g < NG; ++g) {
            const size_t cb = rbase + g * (BN / 2) + tx * 4;
            float4 o;
            o.x = alpha * acc[i][g * 4 + 0];
            o.y = alpha * acc[i][g * 4 + 1];
            o.z = alpha * acc[i][g * 4 + 2];
            o.w = alpha * acc[i][g * 4 + 3];
            if (HAS_D) {
                float4 d4 = *(const float4*)(Dmat + cb);
                o.x = fmaf(beta, d4.x, o.x); o.y = fmaf(beta, d4.y, o.y);
                o.z = fmaf(beta, d4.z, o.z); o.w = fmaf(beta, d4.w, o.w);
            }
            *(float4*)(C + cb) = o;
        }
    }
}

// ---------------------------------------------------------------------------
// Frobenius norm^2 (atomic accumulate) and scale kernels for Newton-Schulz
// ---------------------------------------------------------------------------
__global__ void norm2_kernel(const float* __restrict__ W, float* __restrict__ out, int n)
{
    float ss = 0.f;
    for (int i = (blockIdx.x * 256 + threadIdx.x) * 4; i < n; i += gridDim.x * 256 * 4) {
        float4 w = *(const float4*)(W + i);
        ss += w.x * w.x + w.y * w.y + w.z * w.z + w.w * w.w;
    }
#pragma unroll
    for (int off = 32; off > 0; off >>= 1) ss += __shfl_xor(ss, off);
    __shared__ float red[4];
    if ((threadIdx.x & 63) == 0) red[threadIdx.x >> 6] = ss;
    __syncthreads();
    if (threadIdx.x == 0) atomicAdd(out, red[0] + red[1] + red[2] + red[3]);
}

__global__ void scale_kernel(const float* __restrict__ W, const float* __restrict__ norm2,
                             float* __restrict__ X, int n)
{
    const float s = 1.0f / (sqrtf(*norm2) + 1e-8f);
    const int i = (blockIdx.x * 256 + threadIdx.x) * 4;
    if (i < n) {
        float4 w = *(const float4*)(W + i);
        w.x *= s; w.y *= s; w.z *= s; w.w *= s;
        *(float4*)(X + i) = w;
    }
}

// ---------------------------------------------------------------------------
// Persistent scan kernel: h_t = rms(h_{t-1} @ O_lh^T + u_t)
// 64 WGs x 256 threads. WG wg owns output columns [wg*16, wg*16+16).
// z(t) = pre-norm state; readers normalize on the fly (local sumsq).
// Sync: per-WG monotone step flags, agent-scope fences (cross-XCD safe).
// ---------------------------------------------------------------------------
#define SCAN_WGS   64
#define SCAN_CHUNK 16
#define OPITCH     1028
#define SCAN_LDS_BYTES ((16*OPITCH + 4*OPITCH + 256 + 8) * 4)

__launch_bounds__(256, 1)
__global__ void scan_kernel(const float* __restrict__ O_lh,   // [1024][1024]
                            const float* __restrict__ U,      // [B][T][C]
                            const float* __restrict__ Ident,  // [C]
                            float* __restrict__ QS,           // [B][T][C]
                            float* __restrict__ zbuf,         // [2][B][C]
                            int* __restrict__ flags)          // [64], zero-init
{
    extern __shared__ float lds[];
    float* sO     = lds;                  // [16][OPITCH]
    float* sH     = lds + 16 * OPITCH;    // [4][OPITCH]
    float* sP     = sH + 4 * OPITCH;      // [256] partials
    float* sScale = sP + 256;             // [4]

    const int tid  = threadIdx.x;
    const int wg   = blockIdx.x;
    const int d0   = wg * SCAN_CHUNK;
    const int lane = tid & 63;
    const int wid  = tid >> 6;
    const int dd   = lane & 15;
    const int bb   = lane >> 4;

    // preload O_lh rows [d0, d0+16)
#pragma unroll
    for (int j = 0; j < 16; ++j) {
        const int f = (tid + j * 256) * 4;          // element in 16x1024
        const int row = f >> 10, c = f & 1023;
        float4 v4 = *(const float4*)(O_lh + (size_t)(d0 + row) * C_DIM + c);
        *(float4*)(sO + row * OPITCH + c) = v4;
    }
    __syncthreads();

    for (int t = 1; t <= T_DIM; ++t) {
        // prefetch u row (t-1) — read-only input, safe before any fence
        float uval = 0.f;
        if (tid < 64) uval = U[((size_t)bb * T_DIM + (t - 1)) * C_DIM + d0 + dd];

        if (t > 1) {
            if (wid == 0) {
                const int target = t - 1;
                for (;;) {
                    int fv = __hip_atomic_load(&flags[lane], __ATOMIC_RELAXED,
                                               __HIP_MEMORY_SCOPE_AGENT);
                    if (__all(fv >= target)) break;
                    __builtin_amdgcn_s_sleep(2);
                }
            }
            __syncthreads();
            __builtin_amdgcn_fence(__ATOMIC_ACQUIRE, "agent");

            // stage z(t-1): 16 KB
            const float* zsrc = zbuf + ((t - 1) & 1) * (B_DIM * C_DIM);
#pragma unroll
            for (int j = 0; j < 4; ++j) {
                const int e = (tid + j * 256) * 4;
                const int b = e >> 10, c = e & 1023;
                float4 z4 = *(const float4*)(zsrc + e);
                *(float4*)(sH + b * OPITCH + c) = z4;
            }
            __syncthreads();
            // local sumsq -> rms scale per b
            {
                const int b = tid >> 6, l2 = tid & 63;
                float ss = 0.f;
#pragma unroll
                for (int j = 0; j < 4; ++j) {
                    float4 h4 = *(const float4*)(sH + b * OPITCH + l2 * 16 + j * 4);
                    ss += h4.x * h4.x + h4.y * h4.y + h4.z * h4.z + h4.w * h4.w;
                }
#pragma unroll
                for (int off = 32; off > 0; off >>= 1) ss += __shfl_xor(ss, off);
                if (l2 == 0) sScale[b] = 1.0f / sqrtf(ss * (1.0f / 1024.0f) + 1e-6f);
            }
            __syncthreads();
            // write qs row (t-2) for our chunk (normalized z(t-1))
            if (tid < 64) {
                QS[((size_t)bb * T_DIM + (t - 2)) * C_DIM + d0 + dd] =
                    sH[bb * OPITCH + d0 + dd] * sScale[bb];
            }
        } else {
            // t == 1: h0 = identity (used raw, scale = 1)
            float4 idv = *(const float4*)(Ident + tid * 4);
#pragma unroll
            for (int b = 0; b < 4; ++b)
                *(float4*)(sH + b * OPITCH + tid * 4) = idv;
            if (tid < 4) sScale[tid] = 1.0f;
            __syncthreads();
        }

        // partial dots: wave wid covers c in [wid*256, wid*256+256)
        {
            const float* orow = sO + dd * OPITCH + wid * 256;
            const float* hrow = sH + bb * OPITCH + wid * 256;
            float acc2 = 0.f;
#pragma unroll 8
            for (int k = 0; k < 64; ++k) {
                float4 o4 = *(const float4*)(orow + k * 4);
                float4 h4 = *(const float4*)(hrow + k * 4);
                acc2 = fmaf(o4.x, h4.x, acc2);
                acc2 = fmaf(o4.y, h4.y, acc2);
                acc2 = fmaf(o4.z, h4.z, acc2);
                acc2 = fmaf(o4.w, h4.w, acc2);
            }
            sP[wid * 64 + lane] = acc2;
        }
        __syncthreads();
        if (tid < 64) {
            const float dot = sP[tid] + sP[tid + 64] + sP[tid + 128] + sP[tid + 192];
            const float zn = fmaf(sScale[bb], dot, uval);
            zbuf[(t & 1) * (B_DIM * C_DIM) + bb * C_DIM + d0 + dd] = zn;
        }
        __syncthreads();   // drains vmcnt for all waves before publish
        if (tid == 0) {
            __builtin_amdgcn_fence(__ATOMIC_RELEASE, "agent");
            __hip_atomic_store(&flags[wg], t, __ATOMIC_RELEASE,
                               __HIP_MEMORY_SCOPE_AGENT);
        }
    }

    // epilogue: qs row T-1 from z(T) (buffer parity T&1 == 0)
    {
        if (wid == 0) {
            for (;;) {
                int fv = __hip_atomic_load(&flags[lane], __ATOMIC_RELAXED,
                                           __HIP_MEMORY_SCOPE_AGENT);
                if (__all(fv >= T_DIM)) break;
                __builtin_amdgcn_s_sleep(2);
            }
        }
        __syncthreads();
        __builtin_amdgcn_fence(__ATOMIC_ACQUIRE, "agent");
        const float* zsrc = zbuf + (T_DIM & 1) * (B_DIM * C_DIM);
#pragma unroll
        for (int j = 0; j < 4; ++j) {
            const int e = (tid + j * 256) * 4;
            const int b = e >> 10, c = e & 1023;
            float4 z4 = *(const float4*)(zsrc + e);
            *(float4*)(sH + b * OPITCH + c) = z4;
        }
        __syncthreads();
        {
            const int b = tid >> 6, l2 = tid & 63;
            float ss = 0.f;
#pragma unroll
            for (int j = 0; j < 4; ++j) {
                float4 h4 = *(const float4*)(sH + b * OPITCH + l2 * 16 + j * 4);
                ss += h4.x * h4.x + h4.y * h4.y + h4.z * h4.z + h4.w * h4.w;
            }
#pragma unroll
            for (int off = 32; off > 0; off >>= 1) ss += __shfl_xor(ss, off);
            if (l2 == 0) sScale[b] = 1.0f / sqrtf(ss * (1.0f / 1024.0f) + 1e-6f);
        }
        __syncthreads();
        if (tid < 64) {
            QS[((size_t)bb * T_DIM + (T_DIM - 1)) * C_DIM + d0 + dd] =
                sH[bb * OPITCH + d0 + dd] * sScale[bb];
        }
    }
}

// ---------------------------------------------------------------------------
extern "C" void kernel_launch(void* const* d_in, const int* in_sizes, int n_in,
                              void* d_out, int out_size, void* d_ws, size_t ws_size,
                              hipStream_t stream)
{
    (void)in_sizes; (void)n_in; (void)out_size; (void)ws_size;

    const float* x     = (const float*)d_in[0];
    const float* Wq    = (const float*)d_in[1];
    const float* Wv    = (const float*)d_in[2];
    const float* Wc    = (const float*)d_in[3];
    const float* ident = (const float*)d_in[4];
    const float* Wlh   = (const float*)d_in[5];
    const float* Wrh   = (const float*)d_in[6];

    char* ws = (char*)d_ws;
    int*   flags = (int*)ws;                         // 256 B
    float* norm2 = (float*)(ws + 256);               // 2 floats
    float* zbuf  = (float*)(ws + 4096);              // 32 KB
    float* Xa_lh = (float*)(ws + 65536);             // 5 x 4 MB NS buffers
    float* Xb_lh = Xa_lh + 1048576;
    float* Xa_rh = Xb_lh + 1048576;
    float* Xb_rh = Xa_rh + 1048576;
    float* G     = Xb_rh + 1048576;
    float* V     = G + 1048576;                      // 64 MB

    float* out   = (float*)d_out;
    float* Ybuf  = out;          // first half: u, then Y
    float* QSbuf = out + BTC;    // second half: q, then qs

    const int n2 = C_DIM * C_DIM;

    hipMemsetAsync(d_ws, 0, 4096, stream);   // flags + norm accumulators

    // --- Newton-Schulz prescale
    norm2_kernel<<<dim3(256), dim3(256), 0, stream>>>(Wlh, &norm2[0], n2);
    norm2_kernel<<<dim3(256), dim3(256), 0, stream>>>(Wrh, &norm2[1], n2);
    scale_kernel<<<dim3(1024), dim3(256), 0, stream>>>(Wlh, &norm2[0], Xa_lh, n2);
    scale_kernel<<<dim3(1024), dim3(256), 0, stream>>>(Wrh, &norm2[1], Xa_rh, n2);

    // --- Newton-Schulz iterations: X <- 1.5X - 0.5 (X X^T) X
    float* Xl = Xa_lh; float* Xln = Xb_lh;
    float* Xr = Xa_rh; float* Xrn = Xb_rh;
    const dim3 g64(16, 16), blk(256);
    for (int it = 0; it < 12; ++it) {
        mm_kernel<64,64,16,4,4,true ,false,false><<<g64, blk, 0, stream>>>(
            Xl, Xl, nullptr, nullptr, G, 1024, 1024, 1024, 1.0f, 0.0f);
        mm_kernel<64,64,16,4,4,false,false,true ><<<g64, blk, 0, stream>>>(
            G, Xl, nullptr, Xl, Xln, 1024, 1024, 1024, -0.5f, 1.5f);
        mm_kernel<64,64,16,4,4,true ,false,false><<<g64, blk, 0, stream>>>(
            Xr, Xr, nullptr, nullptr, G, 1024, 1024, 1024, 1.0f, 0.0f);
        mm_kernel<64,64,16,4,4,false,false,true ><<<g64, blk, 0, stream>>>(
            G, Xr, nullptr, Xr, Xrn, 1024, 1024, 1024, -0.5f, 1.5f);
        float* tmp;
        tmp = Xl; Xl = Xln; Xln = tmp;
        tmp = Xr; Xr = Xrn; Xrn = tmp;
    }
    // Xl = O_lh, Xr = O_rh

    // --- big GEMMs: q = x Wq^T (into QS half), v = x Wv^T, u = q O_rh^T (into Y half)
    const dim3 gbig(C_DIM / 128, BT / 128);
    mm_kernel<128,128,16,8,8,true,false,false><<<gbig, blk, 0, stream>>>(
        x, Wq, nullptr, nullptr, QSbuf, BT, C_DIM, C_DIM, 1.0f, 0.0f);
    mm_kernel<128,128,16,8,8,true,false,false><<<gbig, blk, 0, stream>>>(
        x, Wv, nullptr, nullptr, V, BT, C_DIM, C_DIM, 1.0f, 0.0f);
    mm_kernel<128,128,16,8,8,true,false,false><<<gbig, blk, 0, stream>>>(
        QSbuf, Xr, nullptr, nullptr, Ybuf, BT, C_DIM, C_DIM, 1.0f, 0.0f);

    // --- sequential scan (persistent, flag-synced)
    hipFuncSetAttribute((const void*)scan_kernel,
                        hipFuncAttributeMaxDynamicSharedMemorySize, SCAN_LDS_BYTES);
    scan_kernel<<<dim3(SCAN_WGS), dim3(256), SCAN_LDS_BYTES, stream>>>(
        Xl, Ybuf, ident, QSbuf, zbuf, flags);

    // --- Y = (qs * v) Wc^T  (overwrites u region)
    mm_kernel<128,128,16,8,8,true,true,false><<<gbig, blk, 0, stream>>>(
        QSbuf, Wc, V, nullptr, Ybuf, BT, C_DIM, C_DIM, 1.0f, 0.0f);
}

// Round 2
// 13918.840 us; speedup vs baseline: 2.4293x; 2.4293x over previous
//
#include <hip/hip_runtime.h>
#include <math.h>

#define B_DIM 4
#define T_DIM 4096
#define C_DIM 1024
#define BT    (B_DIM*T_DIM)              // 16384
#define BTC   ((size_t)BT*(size_t)C_DIM) // 16777216

// ---------------------------------------------------------------------------
// Generic fp32 tiled matmul (unchanged from R1 — correct, not yet the focus).
//   TB=1: C[m,n] = sum_k A[m,k]*B[n,k]      (B stored [N,K] row-major)
//   TB=0: C[m,n] = sum_k A[m,k]*B[k,n]
//   HAS_A2: A_eff[m,k] = A[m,k]*A2[m,k]
//   out = alpha*acc + (HAS_D ? beta*D[m,n] : 0)
// ---------------------------------------------------------------------------
template<int BM, int BN, int BK, int TM, int TN, bool TB, bool HAS_A2, bool HAS_D>
__launch_bounds__(256)
__global__ void mm_kernel(const float* __restrict__ A,
                          const float* __restrict__ Bmat,
                          const float* __restrict__ A2,
                          const float* __restrict__ Dmat,
                          float* __restrict__ C,
                          int M, int N, int K, float alpha, float beta)
{
    constexpr int NG = TN / 4;
    __shared__ float As[BK][BM + 4];
    __shared__ float Bs[BK][BN + 4];

    const int tid = threadIdx.x;
    const int m0 = blockIdx.y * BM;
    const int n0 = blockIdx.x * BN;
    const int tx = tid & 15;
    const int ty = tid >> 4;

    float acc[TM][TN];
#pragma unroll
    for (int i = 0; i < TM; ++i)
#pragma unroll
        for (int j = 0; j < TN; ++j) acc[i][j] = 0.f;

    for (int k0 = 0; k0 < K; k0 += BK) {
        {
            const int r0 = tid >> 2;
            const int kq = (tid & 3) * 4;
#pragma unroll
            for (int r = 0; r < BM; r += 64) {
                const int row = r + r0;
                float4 a = *(const float4*)(A + (size_t)(m0 + row) * K + k0 + kq);
                if (HAS_A2) {
                    float4 a2 = *(const float4*)(A2 + (size_t)(m0 + row) * K + k0 + kq);
                    a.x *= a2.x; a.y *= a2.y; a.z *= a2.z; a.w *= a2.w;
                }
                As[kq + 0][row] = a.x; As[kq + 1][row] = a.y;
                As[kq + 2][row] = a.z; As[kq + 3][row] = a.w;
            }
        }
        if (TB) {
            const int r0 = tid >> 2;
            const int kq = (tid & 3) * 4;
#pragma unroll
            for (int r = 0; r < BN; r += 64) {
                const int row = r + r0;
                float4 b = *(const float4*)(Bmat + (size_t)(n0 + row) * K + k0 + kq);
                Bs[kq + 0][row] = b.x; Bs[kq + 1][row] = b.y;
                Bs[kq + 2][row] = b.z; Bs[kq + 3][row] = b.w;
            }
        } else {
            constexpr int CPR = BN / 4;
            constexpr int RPP = 256 / CPR;
            const int rr = tid / CPR;
            const int cc = (tid % CPR) * 4;
#pragma unroll
            for (int r = 0; r < BK; r += RPP) {
                float4 b = *(const float4*)(Bmat + (size_t)(k0 + r + rr) * N + n0 + cc);
                *(float4*)(&Bs[r + rr][cc]) = b;
            }
        }
        __syncthreads();

#pragma unroll
        for (int kk = 0; kk < BK; ++kk) {
            float a[TM], b[TN];
#pragma unroll
            for (int i = 0; i < TM; i += 4)
                *(float4*)(&a[i]) = *(const float4*)(&As[kk][ty * TM + i]);
#pragma unroll
            for (int g = 0; g < NG; ++g)
                *(float4*)(&b[g * 4]) = *(const float4*)(&Bs[kk][g * (BN / 2) + tx * 4]);
#pragma unroll
            for (int i = 0; i < TM; ++i)
#pragma unroll
                for (int j = 0; j < TN; ++j)
                    acc[i][j] = fmaf(a[i], b[j], acc[i][j]);
        }
        __syncthreads();
    }

#pragma unroll
    for (int i = 0; i < TM; ++i) {
        const size_t rbase = (size_t)(m0 + ty * TM + i) * N + n0;
#pragma unroll
        for (int g = 0; g < NG; ++g) {
            const size_t cb = rbase + g * (BN / 2) + tx * 4;
            float4 o;
            o.x = alpha * acc[i][g * 4 + 0];
            o.y = alpha * acc[i][g * 4 + 1];
            o.z = alpha * acc[i][g * 4 + 2];
            o.w = alpha * acc[i][g * 4 + 3];
            if (HAS_D) {
                float4 d4 = *(const float4*)(Dmat + cb);
                o.x = fmaf(beta, d4.x, o.x); o.y = fmaf(beta, d4.y, o.y);
                o.z = fmaf(beta, d4.z, o.z); o.w = fmaf(beta, d4.w, o.w);
            }
            *(float4*)(C + cb) = o;
        }
    }
}

// ---------------------------------------------------------------------------
// Newton-Schulz helpers
// ---------------------------------------------------------------------------
__global__ void norm2_kernel(const float* __restrict__ W, float* __restrict__ out, int n)
{
    float ss = 0.f;
    for (int i = (blockIdx.x * 256 + threadIdx.x) * 4; i < n; i += gridDim.x * 256 * 4) {
        float4 w = *(const float4*)(W + i);
        ss += w.x * w.x + w.y * w.y + w.z * w.z + w.w * w.w;
    }
#pragma unroll
    for (int off = 32; off > 0; off >>= 1) ss += __shfl_xor(ss, off);
    __shared__ float red[4];
    if ((threadIdx.x & 63) == 0) red[threadIdx.x >> 6] = ss;
    __syncthreads();
    if (threadIdx.x == 0) atomicAdd(out, red[0] + red[1] + red[2] + red[3]);
}

__global__ void scale_kernel(const float* __restrict__ W, const float* __restrict__ norm2,
                             float* __restrict__ X, int n)
{
    const float s = 1.0f / (sqrtf(*norm2) + 1e-8f);
    const int i = (blockIdx.x * 256 + threadIdx.x) * 4;
    if (i < n) {
        float4 w = *(const float4*)(W + i);
        w.x *= s; w.y *= s; w.z *= s; w.w *= s;
        *(float4*)(X + i) = w;
    }
}

// ---------------------------------------------------------------------------
// Scan v2: fence-free spin-on-data, per-batch chains.
//
// zring: 4 slots x [B][1024] uint32 (fp32 bits with bit0 forced to 1).
// Canary 0xAAAAAAAA (bit0=0) marks "not yet written". Slot for z_t = t%4.
// At step t each WG: polls/stages z_{t-1} (slot (t-1)%4), computes rms scale
// locally, writes qs row t-2, re-poisons its chunk of slot (t+1)%4 (dead
// z_{t-3}; safe: any WG at step t implies all WGs completed step t-1), does
// the 16-dim matvec slice, waitcnt vmcnt(0), publishes z_t chunk with
// relaxed agent-scope stores (sc0 sc1 -> coherent at IF, NO buffer_inv/wbl2).
// ---------------------------------------------------------------------------
#define CANARY 0xAAAAAAAAu
#define OPITCH 1028
#define SCAN_LDS_FLOATS (16*OPITCH + 1024 + 64 + 4)
#define SCAN_LDS_BYTES  (SCAN_LDS_FLOATS * 4)

__global__ void scan_init_kernel(const float* __restrict__ ident,
                                 unsigned int* __restrict__ zring)
{
    const int i = blockIdx.x * 256 + threadIdx.x;   // 64 blocks -> 16384 words
    unsigned int v = CANARY;
    if (i < 4096) {                                 // slot 0 = z_0 = identity (all b)
        v = __float_as_uint(ident[i & 1023]) | 1u;
    }
    zring[i] = v;
}

__launch_bounds__(256, 1)
__global__ void scan_kernel(const float* __restrict__ O_lh,   // [1024][1024]
                            const float* __restrict__ U,      // [B][T][C]
                            float* __restrict__ QS,           // [B][T][C]
                            unsigned int* __restrict__ zring) // [4][B][1024]
{
    extern __shared__ float lds[];
    float* sO = lds;                     // [16][OPITCH]
    float* sH = lds + 16 * OPITCH;       // [1024] staged z (this batch)
    float* sP = sH + 1024;               // [64]  matvec partials
    float* sS = sP + 64;                 // [4]   sumsq partials

    const int tid = threadIdx.x;
    const int wg  = blockIdx.x;          // 256 WGs
    const int b   = wg >> 6;             // batch
    const int g   = wg & 63;             // dim-group
    const int d0  = g * 16;

    // stage O_lh rows [d0, d0+16) once
#pragma unroll
    for (int j = 0; j < 16; ++j) {
        const int f = (tid + j * 256) * 4;
        const int row = f >> 10, c = f & 1023;
        float4 v4 = *(const float4*)(O_lh + (size_t)(d0 + row) * C_DIM + c);
        *(float4*)(sO + row * OPITCH + c) = v4;
    }
    __syncthreads();

    const int bbase = b * 1024;

    for (int t = 1; t <= T_DIM + 1; ++t) {
        // prefetch u_t for the 16 writer lanes (plain load, L2-cached)
        float uval = 0.f;
        if (t <= T_DIM && tid < 16)
            uval = U[((size_t)b * T_DIM + (t - 1)) * C_DIM + d0 + tid];

        // ---- poll + stage z_{t-1}: 4 words/thread, data IS the flag
        unsigned int* zs = zring + ((t - 1) & 3) * (B_DIM * 1024) + bbase;
        unsigned int w0, w1, w2, w3;
        {
            unsigned int* p = zs + tid * 4;
            for (;;) {
                w0 = __hip_atomic_load(p + 0, __ATOMIC_RELAXED, __HIP_MEMORY_SCOPE_AGENT);
                w1 = __hip_atomic_load(p + 1, __ATOMIC_RELAXED, __HIP_MEMORY_SCOPE_AGENT);
                w2 = __hip_atomic_load(p + 2, __ATOMIC_RELAXED, __HIP_MEMORY_SCOPE_AGENT);
                w3 = __hip_atomic_load(p + 3, __ATOMIC_RELAXED, __HIP_MEMORY_SCOPE_AGENT);
                if (w0 != CANARY && w1 != CANARY && w2 != CANARY && w3 != CANARY) break;
                __builtin_amdgcn_s_sleep(1);
            }
        }
        float4 z4;
        z4.x = __uint_as_float(w0); z4.y = __uint_as_float(w1);
        z4.z = __uint_as_float(w2); z4.w = __uint_as_float(w3);
        *(float4*)(sH + tid * 4) = z4;

        // local sumsq -> rms scale
        float ss = z4.x * z4.x + z4.y * z4.y + z4.z * z4.z + z4.w * z4.w;
#pragma unroll
        for (int off = 32; off > 0; off >>= 1) ss += __shfl_xor(ss, off);
        if ((tid & 63) == 0) sS[tid >> 6] = ss;
        __syncthreads();
        const float sumsq = sS[0] + sS[1] + sS[2] + sS[3];
        const float s = (t == 1) ? 1.0f
                                 : 1.0f / sqrtf(sumsq * (1.0f / 1024.0f) + 1e-6f);

        // qs row t-2 = normalized z_{t-1} (our 16 dims)
        if (t >= 2 && tid < 16)
            QS[((size_t)b * T_DIM + (t - 2)) * C_DIM + d0 + tid] = sH[d0 + tid] * s;

        if (t <= T_DIM) {
            // re-poison our chunk of slot (t+1)%4 (holds dead z_{t-3})
            if (tid < 16)
                __hip_atomic_store(zring + ((t + 1) & 3) * (B_DIM * 1024) + bbase + d0 + tid,
                                   CANARY, __ATOMIC_RELAXED, __HIP_MEMORY_SCOPE_AGENT);

            // matvec slice: output o = tid&15 (lanes->rows: 2-way LDS, free),
            // k-chunk kc = tid>>4 (64-wide)
            const int o = tid & 15, kc = tid >> 4;
            const float* orow = sO + o * OPITCH + kc * 64;
            const float* hrow = sH + kc * 64;
            float acc = 0.f;
#pragma unroll
            for (int j = 0; j < 16; ++j) {
                float4 o4 = *(const float4*)(orow + j * 4);
                float4 h4 = *(const float4*)(hrow + j * 4);
                acc = fmaf(o4.x, h4.x, acc);
                acc = fmaf(o4.y, h4.y, acc);
                acc = fmaf(o4.z, h4.z, acc);
                acc = fmaf(o4.w, h4.w, acc);
            }
            acc += __shfl_xor(acc, 16);
            acc += __shfl_xor(acc, 32);
            if ((tid & 63) < 16) sP[(tid >> 6) * 16 + (tid & 15)] = acc;
            __syncthreads();

            if (tid < 16) {
                const float dot = sP[tid] + sP[tid + 16] + sP[tid + 32] + sP[tid + 48];
                const float zn = fmaf(s, dot, uval);
                // publish: drain poison store (and all vmem), then relaxed
                // agent store (sc0 sc1 -> visible at IF on completion)
                asm volatile("" ::: "memory");
                __builtin_amdgcn_s_waitcnt(0x0F70);   // vmcnt(0) only
                asm volatile("" ::: "memory");
                __hip_atomic_store(zring + (t & 3) * (B_DIM * 1024) + bbase + d0 + tid,
                                   __float_as_uint(zn) | 1u,
                                   __ATOMIC_RELAXED, __HIP_MEMORY_SCOPE_AGENT);
            }
            // no bottom barrier needed: next iteration's poll cannot succeed
            // until our own lanes (and all WGs) have published z_t.
        }
    }
}

// ---------------------------------------------------------------------------
extern "C" void kernel_launch(void* const* d_in, const int* in_sizes, int n_in,
                              void* d_out, int out_size, void* d_ws, size_t ws_size,
                              hipStream_t stream)
{
    (void)in_sizes; (void)n_in; (void)out_size; (void)ws_size;

    const float* x     = (const float*)d_in[0];
    const float* Wq    = (const float*)d_in[1];
    const float* Wv    = (const float*)d_in[2];
    const float* Wc    = (const float*)d_in[3];
    const float* ident = (const float*)d_in[4];
    const float* Wlh   = (const float*)d_in[5];
    const float* Wrh   = (const float*)d_in[6];

    char* ws = (char*)d_ws;
    float*        norm2 = (float*)(ws + 256);          // 2 floats
    unsigned int* zring = (unsigned int*)(ws + 4096);  // 64 KB: 4 x [B][1024]
    float* Xa_lh = (float*)(ws + (size_t)128 * 1024);  // 5 x 4 MB NS buffers
    float* Xb_lh = Xa_lh + 1048576;
    float* Xa_rh = Xb_lh + 1048576;
    float* Xb_rh = Xa_rh + 1048576;
    float* G     = Xb_rh + 1048576;
    float* V     = G + 1048576;                        // 64 MB

    float* out   = (float*)d_out;
    float* Ybuf  = out;          // first half: u, then Y
    float* QSbuf = out + BTC;    // second half: q, then qs

    const int n2 = C_DIM * C_DIM;

    hipMemsetAsync(ws, 0, 4096, stream);   // norm2 accumulators

    // --- Newton-Schulz prescale
    norm2_kernel<<<dim3(256), dim3(256), 0, stream>>>(Wlh, &norm2[0], n2);
    norm2_kernel<<<dim3(256), dim3(256), 0, stream>>>(Wrh, &norm2[1], n2);
    scale_kernel<<<dim3(1024), dim3(256), 0, stream>>>(Wlh, &norm2[0], Xa_lh, n2);
    scale_kernel<<<dim3(1024), dim3(256), 0, stream>>>(Wrh, &norm2[1], Xa_rh, n2);

    // --- ring init (poison + slot0 = identity)
    scan_init_kernel<<<dim3(64), dim3(256), 0, stream>>>(ident, zring);

    // --- Newton-Schulz iterations: X <- 1.5X - 0.5 (X X^T) X
    float* Xl = Xa_lh; float* Xln = Xb_lh;
    float* Xr = Xa_rh; float* Xrn = Xb_rh;
    const dim3 g64(16, 16), blk(256);
    for (int it = 0; it < 12; ++it) {
        mm_kernel<64,64,16,4,4,true ,false,false><<<g64, blk, 0, stream>>>(
            Xl, Xl, nullptr, nullptr, G, 1024, 1024, 1024, 1.0f, 0.0f);
        mm_kernel<64,64,16,4,4,false,false,true ><<<g64, blk, 0, stream>>>(
            G, Xl, nullptr, Xl, Xln, 1024, 1024, 1024, -0.5f, 1.5f);
        mm_kernel<64,64,16,4,4,true ,false,false><<<g64, blk, 0, stream>>>(
            Xr, Xr, nullptr, nullptr, G, 1024, 1024, 1024, 1.0f, 0.0f);
        mm_kernel<64,64,16,4,4,false,false,true ><<<g64, blk, 0, stream>>>(
            G, Xr, nullptr, Xr, Xrn, 1024, 1024, 1024, -0.5f, 1.5f);
        float* tmp;
        tmp = Xl; Xl = Xln; Xln = tmp;
        tmp = Xr; Xr = Xrn; Xrn = tmp;
    }
    // Xl = O_lh, Xr = O_rh

    // --- big GEMMs: q = x Wq^T (into QS half), v = x Wv^T, u = q O_rh^T
    const dim3 gbig(C_DIM / 128, BT / 128);
    mm_kernel<128,128,16,8,8,true,false,false><<<gbig, blk, 0, stream>>>(
        x, Wq, nullptr, nullptr, QSbuf, BT, C_DIM, C_DIM, 1.0f, 0.0f);
    mm_kernel<128,128,16,8,8,true,false,false><<<gbig, blk, 0, stream>>>(
        x, Wv, nullptr, nullptr, V, BT, C_DIM, C_DIM, 1.0f, 0.0f);
    mm_kernel<128,128,16,8,8,true,false,false><<<gbig, blk, 0, stream>>>(
        QSbuf, Xr, nullptr, nullptr, Ybuf, BT, C_DIM, C_DIM, 1.0f, 0.0f);

    // --- sequential scan (persistent, spin-on-data)
    hipFuncSetAttribute((const void*)scan_kernel,
                        hipFuncAttributeMaxDynamicSharedMemorySize, SCAN_LDS_BYTES);
    scan_kernel<<<dim3(256), dim3(256), SCAN_LDS_BYTES, stream>>>(
        Xl, Ybuf, QSbuf, zring);

    // --- Y = (qs * v) Wc^T  (overwrites u region)
    mm_kernel<128,128,16,8,8,true,true,false><<<gbig, blk, 0, stream>>>(
        QSbuf, Wc, V, nullptr, Ybuf, BT, C_DIM, C_DIM, 1.0f, 0.0f);
}

// Round 3
// 13576.263 us; speedup vs baseline: 2.4906x; 1.0252x over previous
//
#include <hip/hip_runtime.h>
#include <math.h>

#define B_DIM 4
#define T_DIM 4096
#define C_DIM 1024
#define BT    (B_DIM*T_DIM)              // 16384
#define BTC   ((size_t)BT*(size_t)C_DIM) // 16777216

// ---------------------------------------------------------------------------
// Generic fp32 tiled matmul body (shared by single and batched wrappers).
//   TB=1: C[m,n] = sum_k A[m,k]*B[n,k]      (B stored [N,K] row-major)
//   TB=0: C[m,n] = sum_k A[m,k]*B[k,n]
//   HAS_A2: A_eff[m,k] = A[m,k]*A2[m,k]
//   out = alpha*acc + (HAS_D ? beta*D[m,n] : 0)
// ---------------------------------------------------------------------------
template<int BM, int BN, int BK, int TM, int TN, bool TB, bool HAS_A2, bool HAS_D>
__device__ __forceinline__ void mm_body(const float* __restrict__ A,
                                        const float* __restrict__ Bmat,
                                        const float* __restrict__ A2,
                                        const float* __restrict__ Dmat,
                                        float* __restrict__ C,
                                        int M, int N, int K, float alpha, float beta)
{
    constexpr int NG = TN / 4;
    __shared__ float As[BK][BM + 4];
    __shared__ float Bs[BK][BN + 4];

    const int tid = threadIdx.x;
    const int m0 = blockIdx.y * BM;
    const int n0 = blockIdx.x * BN;
    const int tx = tid & 15;
    const int ty = tid >> 4;

    float acc[TM][TN];
#pragma unroll
    for (int i = 0; i < TM; ++i)
#pragma unroll
        for (int j = 0; j < TN; ++j) acc[i][j] = 0.f;

    for (int k0 = 0; k0 < K; k0 += BK) {
        {
            const int r0 = tid >> 2;
            const int kq = (tid & 3) * 4;
#pragma unroll
            for (int r = 0; r < BM; r += 64) {
                const int row = r + r0;
                float4 a = *(const float4*)(A + (size_t)(m0 + row) * K + k0 + kq);
                if (HAS_A2) {
                    float4 a2 = *(const float4*)(A2 + (size_t)(m0 + row) * K + k0 + kq);
                    a.x *= a2.x; a.y *= a2.y; a.z *= a2.z; a.w *= a2.w;
                }
                As[kq + 0][row] = a.x; As[kq + 1][row] = a.y;
                As[kq + 2][row] = a.z; As[kq + 3][row] = a.w;
            }
        }
        if (TB) {
            const int r0 = tid >> 2;
            const int kq = (tid & 3) * 4;
#pragma unroll
            for (int r = 0; r < BN; r += 64) {
                const int row = r + r0;
                float4 b = *(const float4*)(Bmat + (size_t)(n0 + row) * K + k0 + kq);
                Bs[kq + 0][row] = b.x; Bs[kq + 1][row] = b.y;
                Bs[kq + 2][row] = b.z; Bs[kq + 3][row] = b.w;
            }
        } else {
            constexpr int CPR = BN / 4;
            constexpr int RPP = 256 / CPR;
            const int rr = tid / CPR;
            const int cc = (tid % CPR) * 4;
#pragma unroll
            for (int r = 0; r < BK; r += RPP) {
                float4 b = *(const float4*)(Bmat + (size_t)(k0 + r + rr) * N + n0 + cc);
                *(float4*)(&Bs[r + rr][cc]) = b;
            }
        }
        __syncthreads();

#pragma unroll
        for (int kk = 0; kk < BK; ++kk) {
            float a[TM], b[TN];
#pragma unroll
            for (int i = 0; i < TM; i += 4)
                *(float4*)(&a[i]) = *(const float4*)(&As[kk][ty * TM + i]);
#pragma unroll
            for (int g = 0; g < NG; ++g)
                *(float4*)(&b[g * 4]) = *(const float4*)(&Bs[kk][g * (BN / 2) + tx * 4]);
#pragma unroll
            for (int i = 0; i < TM; ++i)
#pragma unroll
                for (int j = 0; j < TN; ++j)
                    acc[i][j] = fmaf(a[i], b[j], acc[i][j]);
        }
        __syncthreads();
    }

#pragma unroll
    for (int i = 0; i < TM; ++i) {
        const size_t rbase = (size_t)(m0 + ty * TM + i) * N + n0;
#pragma unroll
        for (int g = 0; g < NG; ++g) {
            const size_t cb = rbase + g * (BN / 2) + tx * 4;
            float4 o;
            o.x = alpha * acc[i][g * 4 + 0];
            o.y = alpha * acc[i][g * 4 + 1];
            o.z = alpha * acc[i][g * 4 + 2];
            o.w = alpha * acc[i][g * 4 + 3];
            if (HAS_D) {
                float4 d4 = *(const float4*)(Dmat + cb);
                o.x = fmaf(beta, d4.x, o.x); o.y = fmaf(beta, d4.y, o.y);
                o.z = fmaf(beta, d4.z, o.z); o.w = fmaf(beta, d4.w, o.w);
            }
            *(float4*)(C + cb) = o;
        }
    }
}

template<int BM, int BN, int BK, int TM, int TN, bool TB, bool HAS_A2, bool HAS_D>
__launch_bounds__(256)
__global__ void mm_kernel(const float* __restrict__ A, const float* __restrict__ Bmat,
                          const float* __restrict__ A2, const float* __restrict__ Dmat,
                          float* __restrict__ C, int M, int N, int K, float alpha, float beta)
{
    mm_body<BM,BN,BK,TM,TN,TB,HAS_A2,HAS_D>(A, Bmat, A2, Dmat, C, M, N, K, alpha, beta);
}

// batched pair via blockIdx.z
template<int BM, int BN, int BK, int TM, int TN, bool TB, bool HAS_A2, bool HAS_D>
__launch_bounds__(256)
__global__ void mm2_kernel(const float* A0, const float* A1,
                           const float* B0, const float* B1,
                           const float* D0, const float* D1,
                           float* C0, float* C1,
                           int M, int N, int K, float alpha, float beta)
{
    const int z = blockIdx.z;
    mm_body<BM,BN,BK,TM,TN,TB,HAS_A2,HAS_D>(z ? A1 : A0, z ? B1 : B0, nullptr,
                                            z ? D1 : D0, z ? C1 : C0,
                                            M, N, K, alpha, beta);
}

// ---------------------------------------------------------------------------
// Newton-Schulz helpers
// ---------------------------------------------------------------------------
__global__ void norm2_kernel(const float* __restrict__ W, float* __restrict__ out, int n)
{
    float ss = 0.f;
    for (int i = (blockIdx.x * 256 + threadIdx.x) * 4; i < n; i += gridDim.x * 256 * 4) {
        float4 w = *(const float4*)(W + i);
        ss += w.x * w.x + w.y * w.y + w.z * w.z + w.w * w.w;
    }
#pragma unroll
    for (int off = 32; off > 0; off >>= 1) ss += __shfl_xor(ss, off);
    __shared__ float red[4];
    if ((threadIdx.x & 63) == 0) red[threadIdx.x >> 6] = ss;
    __syncthreads();
    if (threadIdx.x == 0) atomicAdd(out, red[0] + red[1] + red[2] + red[3]);
}

__global__ void scale_kernel(const float* __restrict__ W, const float* __restrict__ norm2,
                             float* __restrict__ X, int n)
{
    const float s = 1.0f / (sqrtf(*norm2) + 1e-8f);
    const int i = (blockIdx.x * 256 + threadIdx.x) * 4;
    if (i < n) {
        float4 w = *(const float4*)(W + i);
        w.x *= s; w.y *= s; w.z *= s; w.w *= s;
        *(float4*)(X + i) = w;
    }
}

// ---------------------------------------------------------------------------
// Scan v3: spin-on-data protocol (as v2) + O_lh in REGISTERS (no sO LDS reads)
// + conflict-free padded h staging + single barrier per step.
//
// Thread roles (256 threads, WG owns 16 output dims, 1 batch):
//   rg = tid&7  -> output rows {d0+2rg, d0+2rg+1}
//   kg = tid>>3 -> k-range [kg*32, kg*32+32)
//   O in regs: o0[32], o1[32] (64 VGPRs). FMA reads h chunk kg from LDS
//   (staged by the 8 same-wave lanes that polled it -> no barrier needed).
// zring: 4 slots x [B][1024]; valid words have bit0=1, canary 0xAA.. bit0=0.
// ---------------------------------------------------------------------------
#define CANARY 0xAAAAAAAAu
#define HPITCH 36    // 32-float chunk + 4 pad: banks 4*(kg+j) mod 32 distinct

__global__ void scan_init_kernel(const float* __restrict__ ident,
                                 unsigned int* __restrict__ zring)
{
    const int i = blockIdx.x * 256 + threadIdx.x;   // 64 blocks -> 16384 words
    unsigned int v = CANARY;
    if (i < 4096) {                                 // slot 0 = z_0 = identity
        v = __float_as_uint(ident[i & 1023]) | 1u;
    }
    zring[i] = v;
}

__launch_bounds__(256, 1)
__global__ void scan_kernel(const float* __restrict__ O_lh,   // [1024][1024]
                            const float* __restrict__ U,      // [B][T][C]
                            float* __restrict__ QS,           // [B][T][C]
                            unsigned int* __restrict__ zring) // [4][B][1024]
{
    __shared__ float sHp[32 * HPITCH];   // 1152 floats
    __shared__ float sP[64];             // dot partials: [wave][16 outputs]
    __shared__ float sS[4];              // sumsq partials per wave

    const int tid  = threadIdx.x;
    const int wg   = blockIdx.x;         // 256 WGs
    const int b    = wg >> 6;            // batch
    const int g    = wg & 63;            // dim-group
    const int d0   = g * 16;
    const int rg   = tid & 7;
    const int kg   = tid >> 3;           // 0..31
    const int wid  = tid >> 6;
    const int lane = tid & 63;

    // ---- O_lh rows into registers: rows d0+2rg, d0+2rg+1; k in [kg*32, +32)
    float o0[32], o1[32];
    {
        const float* r0p = O_lh + (size_t)(d0 + 2 * rg) * C_DIM + kg * 32;
        const float* r1p = r0p + C_DIM;
#pragma unroll
        for (int j = 0; j < 8; ++j) {
            float4 a = *(const float4*)(r0p + j * 4);
            o0[j * 4 + 0] = a.x; o0[j * 4 + 1] = a.y;
            o0[j * 4 + 2] = a.z; o0[j * 4 + 3] = a.w;
            float4 c = *(const float4*)(r1p + j * 4);
            o1[j * 4 + 0] = c.x; o1[j * 4 + 1] = c.y;
            o1[j * 4 + 2] = c.z; o1[j * 4 + 3] = c.w;
        }
    }

    const int bbase = b * 1024;

    for (int t = 1; t <= T_DIM + 1; ++t) {
        // prefetch u_t for the 16 writer lanes (independent, hides latency)
        float uval = 0.f;
        if (t <= T_DIM && tid < 16)
            uval = U[((size_t)b * T_DIM + (t - 1)) * C_DIM + d0 + tid];

        // ---- poll z_{t-1}: 2 x 64-bit agent loads, bit0 tag = validity
        unsigned long long q0, q1;
        {
            unsigned long long* p = (unsigned long long*)
                (zring + ((t - 1) & 3) * (B_DIM * 1024) + bbase + tid * 4);
            for (;;) {
                q0 = __hip_atomic_load(p,     __ATOMIC_RELAXED, __HIP_MEMORY_SCOPE_AGENT);
                q1 = __hip_atomic_load(p + 1, __ATOMIC_RELAXED, __HIP_MEMORY_SCOPE_AGENT);
                const unsigned long long m = q0 & q1;
                if (m & (m >> 32) & 1ull) break;
                __builtin_amdgcn_s_sleep(1);
            }
        }
        float4 z4;
        z4.x = __uint_as_float((unsigned int)q0);
        z4.y = __uint_as_float((unsigned int)(q0 >> 32));
        z4.z = __uint_as_float((unsigned int)q1);
        z4.w = __uint_as_float((unsigned int)(q1 >> 32));
        // stage own 4 words of chunk kg=tid>>3 (same-wave consumers -> no barrier)
        *(float4*)(sHp + kg * HPITCH + rg * 4) = z4;

        // sumsq partial -> per-wave reduce -> sS
        float ss = z4.x * z4.x + z4.y * z4.y + z4.z * z4.z + z4.w * z4.w;
#pragma unroll
        for (int off = 32; off > 0; off >>= 1) ss += __shfl_xor(ss, off);
        if (lane == 0) sS[wid] = ss;

        // ---- matvec: 2 rows x 32 k from registers, h chunk broadcast from LDS
        {
            const float* hb = sHp + kg * HPITCH;
            float acc0 = 0.f, acc1 = 0.f;
#pragma unroll
            for (int j = 0; j < 8; ++j) {
                float4 h4 = *(const float4*)(hb + j * 4);
                acc0 = fmaf(o0[j * 4 + 0], h4.x, acc0);
                acc0 = fmaf(o0[j * 4 + 1], h4.y, acc0);
                acc0 = fmaf(o0[j * 4 + 2], h4.z, acc0);
                acc0 = fmaf(o0[j * 4 + 3], h4.w, acc0);
                acc1 = fmaf(o1[j * 4 + 0], h4.x, acc1);
                acc1 = fmaf(o1[j * 4 + 1], h4.y, acc1);
                acc1 = fmaf(o1[j * 4 + 2], h4.z, acc1);
                acc1 = fmaf(o1[j * 4 + 3], h4.w, acc1);
            }
            // reduce over the wave's 8 k-groups (tid bits 3..5)
            acc0 += __shfl_xor(acc0, 8);  acc1 += __shfl_xor(acc1, 8);
            acc0 += __shfl_xor(acc0, 16); acc1 += __shfl_xor(acc1, 16);
            acc0 += __shfl_xor(acc0, 32); acc1 += __shfl_xor(acc1, 32);
            if (lane < 8) {
                sP[wid * 16 + rg * 2 + 0] = acc0;
                sP[wid * 16 + rg * 2 + 1] = acc1;
            }
        }
        __syncthreads();   // sS + sP + cross-wave sHp (for qs write) visible

        const float sumsq = sS[0] + sS[1] + sS[2] + sS[3];
        const float s = (t == 1) ? 1.0f
                                 : 1.0f / sqrtf(sumsq * (1.0f / 1024.0f) + 1e-6f);

        // qs row t-2 = normalized z_{t-1} (our 16 dims)
        if (t >= 2 && tid < 16) {
            const int k = d0 + tid;
            QS[((size_t)b * T_DIM + (t - 2)) * C_DIM + k] =
                sHp[(k >> 5) * HPITCH + (k & 31)] * s;
        }

        if (t <= T_DIM) {
            if (tid < 16) {
                // re-poison slot (t+1)%4 (dead z_{t-3}); drained before publish
                __hip_atomic_store(zring + ((t + 1) & 3) * (B_DIM * 1024) + bbase + d0 + tid,
                                   CANARY, __ATOMIC_RELAXED, __HIP_MEMORY_SCOPE_AGENT);
                const float dot = sP[tid] + sP[tid + 16] + sP[tid + 32] + sP[tid + 48];
                const float zn = fmaf(s, dot, uval);
                asm volatile("" ::: "memory");
                __builtin_amdgcn_s_waitcnt(0x0F70);   // vmcnt(0)
                asm volatile("" ::: "memory");
                __hip_atomic_store(zring + (t & 3) * (B_DIM * 1024) + bbase + d0 + tid,
                                   __float_as_uint(zn) | 1u,
                                   __ATOMIC_RELAXED, __HIP_MEMORY_SCOPE_AGENT);
            }
            // no bottom barrier: next poll can't succeed until all WGs (incl.
            // our lanes 0..15, lockstep within wave 0) published z_t.
        }
    }
}

// ---------------------------------------------------------------------------
extern "C" void kernel_launch(void* const* d_in, const int* in_sizes, int n_in,
                              void* d_out, int out_size, void* d_ws, size_t ws_size,
                              hipStream_t stream)
{
    (void)in_sizes; (void)n_in; (void)out_size;

    const float* x     = (const float*)d_in[0];
    const float* Wq    = (const float*)d_in[1];
    const float* Wv    = (const float*)d_in[2];
    const float* Wc    = (const float*)d_in[3];
    const float* ident = (const float*)d_in[4];
    const float* Wlh   = (const float*)d_in[5];
    const float* Wrh   = (const float*)d_in[6];

    char* ws = (char*)d_ws;
    float*        norm2 = (float*)(ws + 256);
    unsigned int* zring = (unsigned int*)(ws + 4096);  // 64 KB
    float* Xa_lh = (float*)(ws + (size_t)128 * 1024);
    float* Xb_lh = Xa_lh + 1048576;
    float* Xa_rh = Xb_lh + 1048576;
    float* Xb_rh = Xa_rh + 1048576;
    float* G     = Xb_rh + 1048576;

    const size_t batched_need = (size_t)128 * 1024 + 6u * 4194304u + 67108864u;
    const bool batched = ws_size >= batched_need;

    float* G2 = G + (batched ? 1048576 : 0);           // only valid if batched
    float* V  = G + (batched ? 2 * 1048576 : 1048576); // 64 MB

    float* out   = (float*)d_out;
    float* Ybuf  = out;          // first half: u, then Y
    float* QSbuf = out + BTC;    // second half: q, then qs

    const int n2 = C_DIM * C_DIM;

    hipMemsetAsync(ws, 0, 4096, stream);   // norm2 accumulators

    // --- Newton-Schulz prescale
    norm2_kernel<<<dim3(256), dim3(256), 0, stream>>>(Wlh, &norm2[0], n2);
    norm2_kernel<<<dim3(256), dim3(256), 0, stream>>>(Wrh, &norm2[1], n2);
    scale_kernel<<<dim3(1024), dim3(256), 0, stream>>>(Wlh, &norm2[0], Xa_lh, n2);
    scale_kernel<<<dim3(1024), dim3(256), 0, stream>>>(Wrh, &norm2[1], Xa_rh, n2);

    // --- ring init (poison + slot0 = identity)
    scan_init_kernel<<<dim3(64), dim3(256), 0, stream>>>(ident, zring);

    // --- Newton-Schulz iterations: X <- 1.5X - 0.5 (X X^T) X
    float* Xl = Xa_lh; float* Xln = Xb_lh;
    float* Xr = Xa_rh; float* Xrn = Xb_rh;
    const dim3 blk(256);
    if (batched) {
        const dim3 g64b(16, 16, 2);
        for (int it = 0; it < 12; ++it) {
            mm2_kernel<64,64,16,4,4,true ,false,false><<<g64b, blk, 0, stream>>>(
                Xl, Xr, Xl, Xr, nullptr, nullptr, G, G2, 1024, 1024, 1024, 1.0f, 0.0f);
            mm2_kernel<64,64,16,4,4,false,false,true ><<<g64b, blk, 0, stream>>>(
                G, G2, Xl, Xr, Xl, Xr, Xln, Xrn, 1024, 1024, 1024, -0.5f, 1.5f);
            float* tmp;
            tmp = Xl; Xl = Xln; Xln = tmp;
            tmp = Xr; Xr = Xrn; Xrn = tmp;
        }
    } else {
        const dim3 g64(16, 16);
        for (int it = 0; it < 12; ++it) {
            mm_kernel<64,64,16,4,4,true ,false,false><<<g64, blk, 0, stream>>>(
                Xl, Xl, nullptr, nullptr, G, 1024, 1024, 1024, 1.0f, 0.0f);
            mm_kernel<64,64,16,4,4,false,false,true ><<<g64, blk, 0, stream>>>(
                G, Xl, nullptr, Xl, Xln, 1024, 1024, 1024, -0.5f, 1.5f);
            mm_kernel<64,64,16,4,4,true ,false,false><<<g64, blk, 0, stream>>>(
                Xr, Xr, nullptr, nullptr, G, 1024, 1024, 1024, 1.0f, 0.0f);
            mm_kernel<64,64,16,4,4,false,false,true ><<<g64, blk, 0, stream>>>(
                G, Xr, nullptr, Xr, Xrn, 1024, 1024, 1024, -0.5f, 1.5f);
            float* tmp;
            tmp = Xl; Xl = Xln; Xln = tmp;
            tmp = Xr; Xr = Xrn; Xrn = tmp;
        }
    }
    // Xl = O_lh, Xr = O_rh

    // --- big GEMMs: q = x Wq^T (into QS half) and v = x Wv^T, batched; then
    //     u = q O_rh^T (into Y half)
    const dim3 gbig(C_DIM / 128, BT / 128);
    const dim3 gbig2(C_DIM / 128, BT / 128, 2);
    mm2_kernel<128,128,16,8,8,true,false,false><<<gbig2, blk, 0, stream>>>(
        x, x, Wq, Wv, nullptr, nullptr, QSbuf, V, BT, C_DIM, C_DIM, 1.0f, 0.0f);
    mm_kernel<128,128,16,8,8,true,false,false><<<gbig, blk, 0, stream>>>(
        QSbuf, Xr, nullptr, nullptr, Ybuf, BT, C_DIM, C_DIM, 1.0f, 0.0f);

    // --- sequential scan (persistent, spin-on-data, O in registers)
    scan_kernel<<<dim3(256), dim3(256), 0, stream>>>(Xl, Ybuf, QSbuf, zring);

    // --- Y = (qs * v) Wc^T  (overwrites u region)
    mm_kernel<128,128,16,8,8,true,true,false><<<gbig, blk, 0, stream>>>(
        QSbuf, Wc, V, nullptr, Ybuf, BT, C_DIM, C_DIM, 1.0f, 0.0f);
}